// Round 7
// baseline (436.801 us; speedup 1.0000x reference)
//
#include <hip/hip_runtime.h>
#include <hip/hip_bf16.h>

#define SEQ 2048
#define NB 8
#define DIM 1024

typedef __attribute__((ext_vector_type(4))) float f32x4;
typedef __attribute__((ext_vector_type(8))) short bf16x8;
typedef __attribute__((ext_vector_type(4))) unsigned short u16x4;

__device__ __forceinline__ unsigned short f2bf(float f) {
    union { float f; unsigned u; } x; x.f = f;
    unsigned r = x.u + 0x7fffu + ((x.u >> 16) & 1u);
    return (unsigned short)(r >> 16);
}
__device__ __forceinline__ float bf2f(unsigned short u) {
    union { unsigned u; float f; } x; x.u = ((unsigned)u) << 16;
    return x.f;
}

// ------------- weight convert: 4x fp32 -> bf16 in one dispatch -------------
__global__ __launch_bounds__(256) void convert_w4(const float* __restrict__ s0,
                                                  const float* __restrict__ s1,
                                                  const float* __restrict__ s2,
                                                  const float* __restrict__ s3,
                                                  unsigned short* __restrict__ out) {
    int sel = blockIdx.y;
    const float* src = sel < 2 ? (sel == 0 ? s0 : s1) : (sel == 2 ? s2 : s3);
    int i = blockIdx.x * 256 + threadIdx.x;
    float4 v = reinterpret_cast<const float4*>(src)[i];
    u16x4 o = { f2bf(v.x), f2bf(v.y), f2bf(v.z), f2bf(v.w) };
    reinterpret_cast<u16x4*>(out + (size_t)sel * DIM * DIM)[i] = o;
}

// ---------------- xb[b][s][d] = bf16(seq[s][b][d]) ----------------
__global__ __launch_bounds__(256) void make_xb(const float* __restrict__ seq,
                                               unsigned short* __restrict__ xb) {
    int sb = blockIdx.x;
    int s = sb >> 3, b = sb & 7;
    const float4* src = reinterpret_cast<const float4*>(seq + (size_t)sb * DIM);
    u16x4* dst = reinterpret_cast<u16x4*>(xb + ((size_t)b * SEQ + s) * DIM);
    int t = threadIdx.x;
    float4 v = src[t];
    u16x4 o = { f2bf(v.x), f2bf(v.y), f2bf(v.z), f2bf(v.w) };
    dst[t] = o;
}

// ---------------- xbT[b][d][s] = bf16(seq[s][b][d]) ----------------
__global__ __launch_bounds__(256) void make_xbT(const float* __restrict__ seq,
                                                unsigned short* __restrict__ xbT) {
    __shared__ unsigned short tile[64][65];
    int s0 = blockIdx.x * 64, d0 = blockIdx.y * 64, b = blockIdx.z;
    int t = threadIdx.x;
    int dx = (t & 15) * 4, sy = t >> 4;
    #pragma unroll
    for (int i = 0; i < 4; ++i) {
        int s = s0 + sy + i * 16;
        float4 v = *reinterpret_cast<const float4*>(seq + ((size_t)s * NB + b) * DIM + d0 + dx);
        tile[sy + i * 16][dx + 0] = f2bf(v.x);
        tile[sy + i * 16][dx + 1] = f2bf(v.y);
        tile[sy + i * 16][dx + 2] = f2bf(v.z);
        tile[sy + i * 16][dx + 3] = f2bf(v.w);
    }
    __syncthreads();
    int sx = (t & 15) * 4, dy = t >> 4;
    #pragma unroll
    for (int i = 0; i < 4; ++i) {
        int d = d0 + dy + i * 16;
        u16x4 o = { tile[sx + 0][dy + i * 16], tile[sx + 1][dy + i * 16],
                    tile[sx + 2][dy + i * 16], tile[sx + 3][dy + i * 16] };
        *reinterpret_cast<u16x4*>(xbT + ((size_t)b * DIM + d) * SEQ + s0 + sx) = o;
    }
}

// =============  128x128 BK=64 ring GEMM, 64 KiB LDS -> 2 blocks/CU  ============
// 4 waves (2m x 2n), wave tile 64x64. r6-proven ring schedule:
//   Ph0: read b0-3 + a0,a1 (12) ; stage A0(u+1) ; MFMA q(01,01)
//   Ph1: read a2,a3      (4)  ; stage A1(u+1) ; MFMA q(23,01)
//   Ph2:                        stage B0(u+2) ; MFMA q(23,23)
//   Ph3:                        stage B1(u+2) ; vmcnt(4) ; MFMA q(01,23)
// WAR audit: all B(u) reads confirmed after Ph0's lgkm+bar -> B(u+2) stage into
// same buf at Ph2/Ph3 safe; A(u+1) targets other buf (last read u-1 Ph1).
// vmcnt(4) leaves B(u+2)'s 4 per-thread loads in flight, confirms A(u+1).
__device__ __forceinline__ void gload16(const unsigned short* g, unsigned short* l) {
    __builtin_amdgcn_global_load_lds((const __attribute__((address_space(1))) void*)g,
                                     (__attribute__((address_space(3))) void*)l,
                                     16, 0, 0);
}

#define MFMA8(I0, J0)                                                                             \
    _Pragma("unroll")                                                                             \
    for (int ks = 0; ks < 2; ++ks)                                                                \
        _Pragma("unroll")                                                                         \
        for (int ii = 0; ii < 2; ++ii)                                                            \
            _Pragma("unroll")                                                                     \
            for (int jj = 0; jj < 2; ++jj)                                                        \
                acc[I0 + ii][J0 + jj] = __builtin_amdgcn_mfma_f32_16x16x32_bf16(                   \
                    a[I0 + ii][ks], b[J0 + jj][ks], acc[I0 + ii][J0 + jj], 0, 0, 0);

// MODE 0: C bf16 = tanh(acc); MODE 1: C f32 = acc*scale (+sC*bz); MODE 2: C bf16 = acc*scale (+sC*bz)
template<int MODE>
__global__ __launch_bounds__(256, 2) void gemm128(
    const unsigned short* __restrict__ A, size_t sA,
    const unsigned short* __restrict__ B, size_t sB,
    void* __restrict__ Cv, size_t sC,
    int ldc, int K, float scale)
{
    __shared__ unsigned short AsF[2 * 2 * 4096];   // [buf(8192)][half(4096)] = 32 KiB
    __shared__ unsigned short BsF[2 * 2 * 4096];   // 32 KiB

    // ---- T1: bijective XCD swizzle (all grids divisible by 8) ----
    const int gx = gridDim.x, gy = gridDim.y;
    const int nwg = gx * gy * gridDim.z;
    const int fid = blockIdx.x + gx * (blockIdx.y + gy * blockIdx.z);
    const int cpx = nwg >> 3;
    const int sw = (fid & 7) * cpx + (fid >> 3);
    const int bx = sw % gx;
    const int rem = sw / gx;
    const int by = rem % gy;
    const int bz = rem / gy;

    const unsigned short* Ab = A + sA * bz;
    const unsigned short* Bb = B + sB * bz;
    const int m0 = by * 128;
    const int n0 = bx * 128;

    const int t_ = threadIdx.x;
    const int lane = t_ & 63;
    const int w = t_ >> 6;          // 0..3
    const int wm = w >> 1;          // 0..1 -> A half (64 rows)
    const int wn = w & 1;           // 0..1 -> B half (64 cols)

    const int l3 = lane >> 3;
    const int g7 = lane & 7;
    const size_t h64 = (size_t)64 * K;      // half-tile row offset
    const size_t r8 = (size_t)8 * K;        // +8 rows
    // pre-swizzled source: LDS[row][g] holds global[row][g ^ (row&7)]
    const unsigned short* gA = Ab + (size_t)(m0 + w * 16 + l3) * K + ((g7 ^ l3) << 3);
    const unsigned short* gB = Bb + (size_t)(n0 + w * 16 + l3) * K + ((g7 ^ l3) << 3);

    // read-side fragment addressing (row&7 == lane&7 for row = i*16+fr)
    const int fr = lane & 15;
    const int hi4 = lane >> 4;
    const int off0 = fr * 64 + (((hi4) ^ g7) << 3);
    const int off1 = fr * 64 + (((4 + hi4) ^ g7) << 3);
    const int wlds = w * 1024;

    f32x4 acc[4][4] = {};
    const int NT = K >> 6;

    // ---- prologue: tile0 {A0,A1,B0,B1} -> buf0; tile1 {B0,B1} -> buf1 ----
    gload16(gA, AsF + wlds);                   gload16(gA + r8, AsF + wlds + 512);
    gload16(gA + h64, AsF + 4096 + wlds);      gload16(gA + h64 + r8, AsF + 4096 + wlds + 512);
    gload16(gB, BsF + wlds);                   gload16(gB + r8, BsF + wlds + 512);
    gload16(gB + h64, BsF + 4096 + wlds);      gload16(gB + h64 + r8, BsF + 4096 + wlds + 512);
    {
        const unsigned short* gb1 = gB + 64;
        gload16(gb1, BsF + 8192 + wlds);              gload16(gb1 + r8, BsF + 8192 + wlds + 512);
        gload16(gb1 + h64, BsF + 8192 + 4096 + wlds); gload16(gb1 + h64 + r8, BsF + 8192 + 4096 + wlds + 512);
    }
    asm volatile("s_waitcnt vmcnt(4)" ::: "memory");   // tile0 landed; B(1) in flight
    __builtin_amdgcn_s_barrier();

    const unsigned short* gA1 = gA + 64;     // A(u+1) source
    const unsigned short* gB2 = gB + 128;    // B(u+2) source

    for (int u = 0; u < NT; ++u) {
        const int bu = (u & 1) * 8192;           // current buf
        const int bn = 8192 - bu;                // next buf
        const unsigned short* pA = AsF + bu + wm * 4096;
        const unsigned short* pB = BsF + bu + wn * 4096;
        const bool pfA = (u + 1 < NT);
        const bool pfB = (u + 2 < NT);
        bf16x8 a[4][2], b[4][2];

        // ---------- Ph0: read b0-3 + a0,a1 ; stage A0(u+1) ; MFMA q(01,01) ----------
        #pragma unroll
        for (int j = 0; j < 2; ++j) {
            b[j][0] = *(const bf16x8*)&pB[j * 1024 + off0];
            b[j][1] = *(const bf16x8*)&pB[j * 1024 + off1];
        }
        #pragma unroll
        for (int i = 0; i < 2; ++i) {
            a[i][0] = *(const bf16x8*)&pA[i * 1024 + off0];
            a[i][1] = *(const bf16x8*)&pA[i * 1024 + off1];
        }
        #pragma unroll
        for (int j = 2; j < 4; ++j) {
            b[j][0] = *(const bf16x8*)&pB[j * 1024 + off0];
            b[j][1] = *(const bf16x8*)&pB[j * 1024 + off1];
        }
        if (pfA) { gload16(gA1, AsF + bn + wlds); gload16(gA1 + r8, AsF + bn + wlds + 512); }
        asm volatile("s_waitcnt lgkmcnt(4)" ::: "memory");
        __builtin_amdgcn_s_barrier();
        asm volatile("s_waitcnt lgkmcnt(0)" ::: "memory");
        __builtin_amdgcn_sched_barrier(0);
        __builtin_amdgcn_s_setprio(1);
        MFMA8(0, 0)
        __builtin_amdgcn_s_setprio(0);
        __builtin_amdgcn_s_barrier();

        // ---------- Ph1: read a2,a3 ; stage A1(u+1) ; MFMA q(23,01) ----------
        #pragma unroll
        for (int i = 2; i < 4; ++i) {
            a[i][0] = *(const bf16x8*)&pA[i * 1024 + off0];
            a[i][1] = *(const bf16x8*)&pA[i * 1024 + off1];
        }
        if (pfA) { gload16(gA1 + h64, AsF + bn + 4096 + wlds); gload16(gA1 + h64 + r8, AsF + bn + 4096 + wlds + 512); }
        __builtin_amdgcn_s_barrier();
        asm volatile("s_waitcnt lgkmcnt(0)" ::: "memory");
        __builtin_amdgcn_sched_barrier(0);
        __builtin_amdgcn_s_setprio(1);
        MFMA8(2, 0)
        __builtin_amdgcn_s_setprio(0);
        __builtin_amdgcn_s_barrier();

        // ---------- Ph2: stage B0(u+2) ; MFMA q(23,23) ----------
        if (pfB) { gload16(gB2, BsF + bu + wlds); gload16(gB2 + r8, BsF + bu + wlds + 512); }
        __builtin_amdgcn_s_barrier();
        __builtin_amdgcn_sched_barrier(0);
        __builtin_amdgcn_s_setprio(1);
        MFMA8(2, 2)
        __builtin_amdgcn_s_setprio(0);
        __builtin_amdgcn_s_barrier();

        // ---------- Ph3: stage B1(u+2) ; vmcnt ; MFMA q(01,23) ----------
        if (pfB) {
            gload16(gB2 + h64, BsF + bu + 4096 + wlds);
            gload16(gB2 + h64 + r8, BsF + bu + 4096 + wlds + 512);
            asm volatile("s_waitcnt vmcnt(4)" ::: "memory");   // confirms A(u+1)+older
        } else {
            asm volatile("s_waitcnt vmcnt(0)" ::: "memory");
        }
        __builtin_amdgcn_s_barrier();
        __builtin_amdgcn_sched_barrier(0);
        __builtin_amdgcn_s_setprio(1);
        MFMA8(0, 2)
        __builtin_amdgcn_s_setprio(0);
        __builtin_amdgcn_s_barrier();

        gA1 += 64; gB2 += 64;
    }

    // ---- epilogue: C/D layout col=lane&15, row=(lane>>4)*4+r ----
    #pragma unroll
    for (int mi = 0; mi < 4; ++mi)
        #pragma unroll
        for (int ni = 0; ni < 4; ++ni)
            #pragma unroll
            for (int r = 0; r < 4; ++r) {
                int row = m0 + wm * 64 + mi * 16 + hi4 * 4 + r;
                int col = n0 + wn * 64 + ni * 16 + fr;
                if (MODE == 0) {
                    unsigned short* C = reinterpret_cast<unsigned short*>(Cv);
                    C[(size_t)row * ldc + col] = f2bf(tanhf(acc[mi][ni][r]));
                } else if (MODE == 1) {
                    float* C = reinterpret_cast<float*>(Cv) + sC * bz;
                    C[(size_t)row * ldc + col] = acc[mi][ni][r] * scale;
                } else {
                    unsigned short* C = reinterpret_cast<unsigned short*>(Cv) + sC * bz;
                    C[(size_t)row * ldc + col] = f2bf(acc[mi][ni][r] * scale);
                }
            }
}

// ------------- in-place row softmax on bf16 logits ----------
__global__ __launch_bounds__(256) void softmax_rows_bf16(unsigned short* __restrict__ Z) {
    const size_t row = blockIdx.x;
    unsigned short* z = Z + row * SEQ;
    const int t = threadIdx.x;
    u16x4 v0 = reinterpret_cast<const u16x4*>(z)[2 * t];
    u16x4 v1 = reinterpret_cast<const u16x4*>(z)[2 * t + 1];
    float f[8] = { bf2f(v0[0]), bf2f(v0[1]), bf2f(v0[2]), bf2f(v0[3]),
                   bf2f(v1[0]), bf2f(v1[1]), bf2f(v1[2]), bf2f(v1[3]) };
    float m = f[0];
    #pragma unroll
    for (int j = 1; j < 8; ++j) m = fmaxf(m, f[j]);
    #pragma unroll
    for (int off = 32; off; off >>= 1) m = fmaxf(m, __shfl_xor(m, off, 64));
    __shared__ float redm[4], reds[4];
    const int w = t >> 6, lane = t & 63;
    if (lane == 0) redm[w] = m;
    __syncthreads();
    m = fmaxf(fmaxf(redm[0], redm[1]), fmaxf(redm[2], redm[3]));
    float e[8], s = 0.f;
    #pragma unroll
    for (int j = 0; j < 8; ++j) { e[j] = __expf(f[j] - m); s += e[j]; }
    #pragma unroll
    for (int off = 32; off; off >>= 1) s += __shfl_xor(s, off, 64);
    if (lane == 0) reds[w] = s;
    __syncthreads();
    s = reds[0] + reds[1] + reds[2] + reds[3];
    float inv = 1.0f / s;
    u16x4 o0 = { f2bf(e[0] * inv), f2bf(e[1] * inv), f2bf(e[2] * inv), f2bf(e[3] * inv) };
    u16x4 o1 = { f2bf(e[4] * inv), f2bf(e[5] * inv), f2bf(e[6] * inv), f2bf(e[7] * inv) };
    reinterpret_cast<u16x4*>(z)[2 * t] = o0;
    reinterpret_cast<u16x4*>(z)[2 * t + 1] = o1;
}

// ---------------- launch ----------------
extern "C" void kernel_launch(void* const* d_in, const int* in_sizes, int n_in,
                              void* d_out, int out_size, void* d_ws, size_t ws_size,
                              hipStream_t stream) {
    const float* seq  = (const float*)d_in[0];
    const float* Kw1f = (const float*)d_in[1];
    const float* Kw2f = (const float*)d_in[2];
    const float* Qw1f = (const float*)d_in[3];
    const float* Qw2f = (const float*)d_in[4];
    float* out = (float*)d_out;

    // Workspace (168 MiB): W 8 | xb/qrs 32 | h/xbT 32 | keys 32 | logits(P) 64
    char* ws = (char*)d_ws;
    size_t off = 0;
    auto alloc = [&](size_t bytes) { void* p = ws + off; off += bytes; return p; };
    const size_t WBYTES = (size_t)DIM * DIM * 2;
    const size_t XBYTES = (size_t)NB * SEQ * DIM * 2;
    unsigned short* Wk1 = (unsigned short*)alloc(4 * WBYTES);
    unsigned short* Wk2 = Wk1 + (size_t)DIM * DIM;
    unsigned short* Wq1 = Wk2 + (size_t)DIM * DIM;
    unsigned short* Wq2 = Wq1 + (size_t)DIM * DIM;
    unsigned short* xb   = (unsigned short*)alloc(XBYTES);   // reused as qrs
    unsigned short* hbuf = (unsigned short*)alloc(XBYTES);   // reused as xbT
    unsigned short* keys = (unsigned short*)alloc(XBYTES);
    unsigned short* P    = (unsigned short*)alloc((size_t)NB * SEQ * SEQ * 2);
    unsigned short* qrs = xb;
    unsigned short* xbT = hbuf;

    convert_w4<<<dim3(DIM * DIM / 4 / 256, 4), 256, 0, stream>>>(Kw1f, Kw2f, Qw1f, Qw2f, Wk1);
    make_xb<<<SEQ * NB, 256, 0, stream>>>(seq, xb);

    // MLPs: [16384,1024] x [1024,1024]^T, tanh epilogue
    dim3 gMLP(DIM / 128, (NB * SEQ) / 128, 1);
    gemm128<0><<<gMLP, 256, 0, stream>>>(xb,   0, Wk1, 0, hbuf, 0, DIM, DIM, 1.0f);
    gemm128<0><<<gMLP, 256, 0, stream>>>(hbuf, 0, Wk2, 0, keys, 0, DIM, DIM, 1.0f);
    gemm128<0><<<gMLP, 256, 0, stream>>>(xb,   0, Wq1, 0, hbuf, 0, DIM, DIM, 1.0f);
    gemm128<0><<<gMLP, 256, 0, stream>>>(hbuf, 0, Wq2, 0, qrs,  0, DIM, DIM, 1.0f);

    // logits[b,s,t] = keys[b,s,:].qrs[b,t,:] / sqrt(D)  (bf16 out)
    dim3 gQK(SEQ / 128, SEQ / 128, NB);
    gemm128<2><<<gQK, 256, 0, stream>>>(keys, (size_t)SEQ * DIM, qrs, (size_t)SEQ * DIM,
                                        P, (size_t)SEQ * SEQ, SEQ, DIM, 0.03125f);

    softmax_rows_bf16<<<NB * SEQ, 256, 0, stream>>>(P);

    make_xbT<<<dim3(SEQ / 64, DIM / 64, NB), 256, 0, stream>>>(seq, xbT);

    // attended[b,s,:] = P[b,s,:] @ x[b]; write into out[s, b, :]
    dim3 gPV(DIM / 128, SEQ / 128, NB);
    gemm128<1><<<gPV, 256, 0, stream>>>(P, (size_t)SEQ * SEQ, xbT, (size_t)DIM * SEQ,
                                        out, (size_t)DIM, NB * DIM, SEQ, 1.0f);
}

// Round 8
// 369.057 us; speedup vs baseline: 1.1836x; 1.1836x over previous
//
#include <hip/hip_runtime.h>
#include <hip/hip_bf16.h>

#define SEQ 2048
#define NB 8
#define DIM 1024

typedef __attribute__((ext_vector_type(4))) float f32x4;
typedef __attribute__((ext_vector_type(8))) short bf16x8;
typedef __attribute__((ext_vector_type(4))) unsigned short u16x4;

__device__ __forceinline__ unsigned short f2bf(float f) {
    union { float f; unsigned u; } x; x.f = f;
    unsigned r = x.u + 0x7fffu + ((x.u >> 16) & 1u);
    return (unsigned short)(r >> 16);
}
__device__ __forceinline__ float bf2f(unsigned short u) {
    union { unsigned u; float f; } x; x.u = ((unsigned)u) << 16;
    return x.f;
}

// ------------- weight convert: slabs [Kw1, Qw1, Kw2, Qw2] -------------
__global__ __launch_bounds__(256) void convert_w4(const float* __restrict__ kw1,
                                                  const float* __restrict__ kw2,
                                                  const float* __restrict__ qw1,
                                                  const float* __restrict__ qw2,
                                                  unsigned short* __restrict__ out) {
    int sel = blockIdx.y;   // 0:Kw1 1:Qw1 2:Kw2 3:Qw2
    const float* src = sel == 0 ? kw1 : (sel == 1 ? qw1 : (sel == 2 ? kw2 : qw2));
    int i = blockIdx.x * 256 + threadIdx.x;
    float4 v = reinterpret_cast<const float4*>(src)[i];
    u16x4 o = { f2bf(v.x), f2bf(v.y), f2bf(v.z), f2bf(v.w) };
    reinterpret_cast<u16x4*>(out + (size_t)sel * DIM * DIM)[i] = o;
}

// ---------------- xb[b][s][d] = bf16(seq[s][b][d]) ----------------
__global__ __launch_bounds__(256) void make_xb(const float* __restrict__ seq,
                                               unsigned short* __restrict__ xb) {
    int sb = blockIdx.x;
    int s = sb >> 3, b = sb & 7;
    const float4* src = reinterpret_cast<const float4*>(seq + (size_t)sb * DIM);
    u16x4* dst = reinterpret_cast<u16x4*>(xb + ((size_t)b * SEQ + s) * DIM);
    int t = threadIdx.x;
    float4 v = src[t];
    u16x4 o = { f2bf(v.x), f2bf(v.y), f2bf(v.z), f2bf(v.w) };
    dst[t] = o;
}

// ---------------- xbT[b][d][s] = bf16(seq[s][b][d]) ----------------
__global__ __launch_bounds__(256) void make_xbT(const float* __restrict__ seq,
                                                unsigned short* __restrict__ xbT) {
    __shared__ unsigned short tile[64][65];
    int s0 = blockIdx.x * 64, d0 = blockIdx.y * 64, b = blockIdx.z;
    int t = threadIdx.x;
    int dx = (t & 15) * 4, sy = t >> 4;
    #pragma unroll
    for (int i = 0; i < 4; ++i) {
        int s = s0 + sy + i * 16;
        float4 v = *reinterpret_cast<const float4*>(seq + ((size_t)s * NB + b) * DIM + d0 + dx);
        tile[sy + i * 16][dx + 0] = f2bf(v.x);
        tile[sy + i * 16][dx + 1] = f2bf(v.y);
        tile[sy + i * 16][dx + 2] = f2bf(v.z);
        tile[sy + i * 16][dx + 3] = f2bf(v.w);
    }
    __syncthreads();
    int sx = (t & 15) * 4, dy = t >> 4;
    #pragma unroll
    for (int i = 0; i < 4; ++i) {
        int d = d0 + dy + i * 16;
        u16x4 o = { tile[sx + 0][dy + i * 16], tile[sx + 1][dy + i * 16],
                    tile[sx + 2][dy + i * 16], tile[sx + 3][dy + i * 16] };
        *reinterpret_cast<u16x4*>(xbT + ((size_t)b * DIM + d) * SEQ + s0 + sx) = o;
    }
}

// ---------------- rowsum zero ----------------
__global__ __launch_bounds__(256) void zero_rowsum(float* __restrict__ rs) {
    rs[blockIdx.x * 256 + threadIdx.x] = 0.0f;
}

// =====================  256x256 8-phase GEMM (r6 ring, + lda/ldb + modes) =====
// MODE 0: C bf16 = tanh(acc)            (+sC*bz)
// MODE 3: C bf16 = exp(acc*scale); per-row partial sums atomicAdd -> rowsum[bz*SEQ+row]
// MODE 4: C f32  = acc / rowsum[bz*SEQ+row]   (+sC*bz)
__device__ __forceinline__ void gload16(const unsigned short* g, unsigned short* l) {
    __builtin_amdgcn_global_load_lds((const __attribute__((address_space(1))) void*)g,
                                     (__attribute__((address_space(3))) void*)l,
                                     16, 0, 0);
}

#define MFMA16(I0, J0)                                                                            \
    _Pragma("unroll")                                                                             \
    for (int ks = 0; ks < 2; ++ks)                                                                \
        _Pragma("unroll")                                                                         \
        for (int ii = 0; ii < 4; ++ii)                                                            \
            _Pragma("unroll")                                                                     \
            for (int jj = 0; jj < 2; ++jj)                                                        \
                acc[I0 + ii][J0 + jj] = __builtin_amdgcn_mfma_f32_16x16x32_bf16(                   \
                    a[I0 + ii][ks], b[J0 + jj][ks], acc[I0 + ii][J0 + jj], 0, 0, 0);

template<int MODE>
__global__ __launch_bounds__(512, 2) void gemm256(
    const unsigned short* __restrict__ A, size_t sA, int lda,
    const unsigned short* __restrict__ B, size_t sB, int ldb,
    void* __restrict__ Cv, size_t sC, int ldc,
    int K, float scale, float* __restrict__ rowsum)
{
    __shared__ unsigned short AsF[2 * 2 * 8192];
    __shared__ unsigned short BsF[2 * 2 * 8192];

    // ---- T1: bijective XCD swizzle (all grids divisible by 8) ----
    const int gx = gridDim.x, gy = gridDim.y;
    const int nwg = gx * gy * gridDim.z;
    const int fid = blockIdx.x + gx * (blockIdx.y + gy * blockIdx.z);
    const int cpx = nwg >> 3;
    const int sw = (fid & 7) * cpx + (fid >> 3);
    const int bx = sw % gx;
    const int rem = sw / gx;
    const int by = rem % gy;
    const int bz = rem / gy;

    const unsigned short* Ab = A + sA * bz;
    const unsigned short* Bb = B + sB * bz;
    const int m0 = by * 256;
    const int n0 = bx * 256;

    const int t_ = threadIdx.x;
    const int lane = t_ & 63;
    const int w = t_ >> 6;
    const int wm = w >> 2;
    const int wn = w & 3;

    const int l3 = lane >> 3;
    const int g7 = lane & 7;
    const size_t h128a = (size_t)128 * lda, r8a = (size_t)8 * lda;
    const size_t h128b = (size_t)128 * ldb, r8b = (size_t)8 * ldb;
    // pre-swizzled source: LDS[row][g] holds global[row][g ^ (row&7)]
    const unsigned short* gA = Ab + (size_t)(m0 + w * 16 + l3) * lda + ((g7 ^ l3) << 3);
    const unsigned short* gB = Bb + (size_t)(n0 + w * 16 + l3) * ldb + ((g7 ^ l3) << 3);

    const int fr = lane & 15;
    const int hi4 = lane >> 4;
    const int off0 = fr * 64 + (((hi4) ^ g7) << 3);
    const int off1 = fr * 64 + (((4 + hi4) ^ g7) << 3);
    const int bno = (wn & 1) * 4096;
    const int wlds = w * 1024;

    f32x4 acc[8][4] = {};
    const int NT = K >> 6;

    // ---- prologue: tile0 {A0,A1,B0,B1} -> buf0; tile1 {B0,B1} -> buf1 ----
    gload16(gA, AsF + wlds);                     gload16(gA + r8a, AsF + wlds + 512);
    gload16(gA + h128a, AsF + 8192 + wlds);      gload16(gA + h128a + r8a, AsF + 8192 + wlds + 512);
    gload16(gB, BsF + wlds);                     gload16(gB + r8b, BsF + wlds + 512);
    gload16(gB + h128b, BsF + 8192 + wlds);      gload16(gB + h128b + r8b, BsF + 8192 + wlds + 512);
    {
        const unsigned short* gb1 = gB + 64;
        gload16(gb1, BsF + 16384 + wlds);                gload16(gb1 + r8b, BsF + 16384 + wlds + 512);
        gload16(gb1 + h128b, BsF + 16384 + 8192 + wlds); gload16(gb1 + h128b + r8b, BsF + 16384 + 8192 + wlds + 512);
    }
    asm volatile("s_waitcnt vmcnt(4)" ::: "memory");
    __builtin_amdgcn_s_barrier();

    const unsigned short* gA1 = gA + 64;
    const unsigned short* gB2 = gB + 128;

    for (int u = 0; u < NT; ++u) {
        const int bu = (u & 1) * 16384;
        const int bn = 16384 - bu;
        const unsigned short* pA = AsF + bu + wm * 8192;
        const unsigned short* pB = BsF + bu + (wn >> 1) * 8192 + bno;
        const bool pfA = (u + 1 < NT);
        const bool pfB = (u + 2 < NT);
        bf16x8 a[8][2], b[4][2];

        // ---------- Ph0: read a0-3 + b01 ; stage A0(u+1) ; MFMA q00 ----------
        #pragma unroll
        for (int i = 0; i < 4; ++i) {
            a[i][0] = *(const bf16x8*)&pA[i * 1024 + off0];
            a[i][1] = *(const bf16x8*)&pA[i * 1024 + off1];
        }
        #pragma unroll
        for (int j = 0; j < 2; ++j) {
            b[j][0] = *(const bf16x8*)&pB[j * 1024 + off0];
            b[j][1] = *(const bf16x8*)&pB[j * 1024 + off1];
        }
        if (pfA) { gload16(gA1, AsF + bn + wlds); gload16(gA1 + r8a, AsF + bn + wlds + 512); }
        asm volatile("s_waitcnt lgkmcnt(8)" ::: "memory");
        __builtin_amdgcn_s_barrier();
        asm volatile("s_waitcnt lgkmcnt(0)" ::: "memory");
        __builtin_amdgcn_sched_barrier(0);
        __builtin_amdgcn_s_setprio(1);
        MFMA16(0, 0)
        __builtin_amdgcn_s_setprio(0);
        __builtin_amdgcn_s_barrier();

        // ---------- Ph1: read b23 ; stage A1(u+1) ; MFMA q01 ----------
        #pragma unroll
        for (int j = 2; j < 4; ++j) {
            b[j][0] = *(const bf16x8*)&pB[j * 1024 + off0];
            b[j][1] = *(const bf16x8*)&pB[j * 1024 + off1];
        }
        if (pfA) { gload16(gA1 + h128a, AsF + bn + 8192 + wlds); gload16(gA1 + h128a + r8a, AsF + bn + 8192 + wlds + 512); }
        __builtin_amdgcn_s_barrier();
        asm volatile("s_waitcnt lgkmcnt(0)" ::: "memory");
        __builtin_amdgcn_sched_barrier(0);
        __builtin_amdgcn_s_setprio(1);
        MFMA16(0, 2)
        __builtin_amdgcn_s_setprio(0);
        __builtin_amdgcn_s_barrier();

        // ---------- Ph2: read a4-7 ; stage B0(u+2) ; MFMA q10 ----------
        #pragma unroll
        for (int i = 4; i < 8; ++i) {
            a[i][0] = *(const bf16x8*)&pA[i * 1024 + off0];
            a[i][1] = *(const bf16x8*)&pA[i * 1024 + off1];
        }
        if (pfB) { gload16(gB2, BsF + bu + wlds); gload16(gB2 + r8b, BsF + bu + wlds + 512); }
        __builtin_amdgcn_s_barrier();
        asm volatile("s_waitcnt lgkmcnt(0)" ::: "memory");
        __builtin_amdgcn_sched_barrier(0);
        __builtin_amdgcn_s_setprio(1);
        MFMA16(4, 0)
        __builtin_amdgcn_s_setprio(0);
        __builtin_amdgcn_s_barrier();

        // ---------- Ph3: stage B1(u+2) ; vmcnt ; MFMA q11 ----------
        if (pfB) {
            gload16(gB2 + h128b, BsF + bu + 8192 + wlds);
            gload16(gB2 + h128b + r8b, BsF + bu + 8192 + wlds + 512);
            asm volatile("s_waitcnt vmcnt(4)" ::: "memory");
        } else {
            asm volatile("s_waitcnt vmcnt(0)" ::: "memory");
        }
        __builtin_amdgcn_s_barrier();
        __builtin_amdgcn_sched_barrier(0);
        __builtin_amdgcn_s_setprio(1);
        MFMA16(4, 2)
        __builtin_amdgcn_s_setprio(0);
        __builtin_amdgcn_s_barrier();

        gA1 += 64; gB2 += 64;
    }

    // ---- epilogue: C/D layout col=lane&15, row=(lane>>4)*4+r ----
    if (MODE == 0) {
        unsigned short* C = reinterpret_cast<unsigned short*>(Cv) + sC * bz;
        #pragma unroll
        for (int mi = 0; mi < 8; ++mi)
            #pragma unroll
            for (int ni = 0; ni < 4; ++ni)
                #pragma unroll
                for (int r = 0; r < 4; ++r) {
                    int row = m0 + wm * 128 + mi * 16 + hi4 * 4 + r;
                    int col = n0 + wn * 64 + ni * 16 + fr;
                    C[(size_t)row * ldc + col] = f2bf(tanhf(acc[mi][ni][r]));
                }
    } else if (MODE == 3) {
        unsigned short* C = reinterpret_cast<unsigned short*>(Cv) + sC * bz;
        #pragma unroll
        for (int mi = 0; mi < 8; ++mi)
            #pragma unroll
            for (int r = 0; r < 4; ++r) {
                int row = m0 + wm * 128 + mi * 16 + hi4 * 4 + r;
                float ps = 0.f;
                #pragma unroll
                for (int ni = 0; ni < 4; ++ni) {
                    unsigned short h = f2bf(__expf(acc[mi][ni][r] * scale));
                    C[(size_t)row * ldc + (n0 + wn * 64 + ni * 16 + fr)] = h;
                    ps += bf2f(h);
                }
                ps += __shfl_xor(ps, 1, 64);
                ps += __shfl_xor(ps, 2, 64);
                ps += __shfl_xor(ps, 4, 64);
                ps += __shfl_xor(ps, 8, 64);
                if (fr == 0) atomicAdd(&rowsum[(size_t)bz * SEQ + row], ps);
            }
    } else {
        float* C = reinterpret_cast<float*>(Cv) + sC * bz;
        #pragma unroll
        for (int mi = 0; mi < 8; ++mi)
            #pragma unroll
            for (int r = 0; r < 4; ++r) {
                int row = m0 + wm * 128 + mi * 16 + hi4 * 4 + r;
                float invs = 1.0f / rowsum[(size_t)bz * SEQ + row];
                #pragma unroll
                for (int ni = 0; ni < 4; ++ni) {
                    int col = n0 + wn * 64 + ni * 16 + fr;
                    C[(size_t)row * ldc + col] = acc[mi][ni][r] * invs;
                }
            }
    }
}

// ---------------- launch ----------------
extern "C" void kernel_launch(void* const* d_in, const int* in_sizes, int n_in,
                              void* d_out, int out_size, void* d_ws, size_t ws_size,
                              hipStream_t stream) {
    const float* seq  = (const float*)d_in[0];
    const float* Kw1f = (const float*)d_in[1];
    const float* Kw2f = (const float*)d_in[2];
    const float* Qw1f = (const float*)d_in[3];
    const float* Qw2f = (const float*)d_in[4];
    float* out = (float*)d_out;

    // Workspace (168 MiB):
    //   [0,8)    W slabs [Kw1,Qw1,Kw2,Qw2]   (dead after MLP2; rowsum reuses offset 0)
    //   [8,40)   xb                          (dead after MLP1)
    //   [40,104) hKQ  [16384 x 2048]         (dead after MLP2)
    //   [104,168) keysqrs [2][8][2048][1024]
    //   P  @ [8,72)   (aliases xb + hKQ-low, alive after MLP2)
    //   xbT@ [72,104) (aliases hKQ-high)
    char* ws = (char*)d_ws;
    const size_t MB = 1024 * 1024;
    unsigned short* W    = (unsigned short*)(ws);
    unsigned short* Wkq1 = W;                                  // [2048,1024]
    unsigned short* Wk2s = W + 2 * (size_t)DIM * DIM;          // Wk2 then Wq2
    unsigned short* xb   = (unsigned short*)(ws + 8 * MB);
    unsigned short* hKQ  = (unsigned short*)(ws + 40 * MB);
    unsigned short* kq   = (unsigned short*)(ws + 104 * MB);   // keys then qrs
    unsigned short* P    = (unsigned short*)(ws + 8 * MB);
    unsigned short* xbT  = (unsigned short*)(ws + 72 * MB);
    float* rowsum        = (float*)(ws);                       // 64 KB, W dead by then

    convert_w4<<<dim3(DIM * DIM / 4 / 256, 4), 256, 0, stream>>>(Kw1f, Kw2f, Qw1f, Qw2f, W);
    make_xb<<<SEQ * NB, 256, 0, stream>>>(seq, xb);

    // MLP1 merged: hKQ[16384,2048] = tanh(xb @ [Wk1;Wq1]^T)
    gemm256<0><<<dim3(2 * DIM / 256, (NB * SEQ) / 256, 1), 512, 0, stream>>>(
        xb, 0, DIM, Wkq1, 0, DIM, hKQ, 0, 2 * DIM, DIM, 1.0f, nullptr);

    // MLP2 batched z=2: keys = tanh(hK @ Wk2^T), qrs = tanh(hQ @ Wq2^T)
    gemm256<0><<<dim3(DIM / 256, (NB * SEQ) / 256, 2), 512, 0, stream>>>(
        hKQ, (size_t)DIM, 2 * DIM, Wk2s, (size_t)DIM * DIM, DIM,
        kq, (size_t)NB * SEQ * DIM, DIM, DIM, 1.0f, nullptr);

    zero_rowsum<<<NB * SEQ / 256, 256, 0, stream>>>(rowsum);
    make_xbT<<<dim3(SEQ / 64, DIM / 64, NB), 256, 0, stream>>>(seq, xbT);

    // QK: P[b,s,t] = exp(keys[b,s,:].qrs[b,t,:]/32), rowsum accumulated
    gemm256<3><<<dim3(SEQ / 256, SEQ / 256, NB), 512, 0, stream>>>(
        kq, (size_t)SEQ * DIM, DIM, kq + (size_t)NB * SEQ * DIM, (size_t)SEQ * DIM, DIM,
        P, (size_t)SEQ * SEQ, SEQ, DIM, 0.03125f, rowsum);

    // PV: out[s,b,:] = (P[b,s,:] @ x[b]) / rowsum[b,s]
    gemm256<4><<<dim3(DIM / 256, SEQ / 256, NB), 512, 0, stream>>>(
        P, (size_t)SEQ * SEQ, SEQ, xbT, (size_t)DIM * SEQ, SEQ,
        out, (size_t)DIM, NB * DIM, SEQ, 1.0f, rowsum);
}

// Round 9
// 348.585 us; speedup vs baseline: 1.2531x; 1.0587x over previous
//
#include <hip/hip_runtime.h>
#include <hip/hip_bf16.h>

#define SEQ 2048
#define NB 8
#define DIM 1024

typedef __attribute__((ext_vector_type(4))) float f32x4;
typedef __attribute__((ext_vector_type(8))) short bf16x8;
typedef __attribute__((ext_vector_type(4))) unsigned short u16x4;

__device__ __forceinline__ unsigned short f2bf(float f) {
    __hip_bfloat16 h = __float2bfloat16(f);           // RNE; compiler can fuse to v_cvt_pk_bf16_f32
    return *reinterpret_cast<unsigned short*>(&h);
}
__device__ __forceinline__ float bf2f(unsigned short u) {
    union { unsigned u; float f; } x; x.u = ((unsigned)u) << 16;
    return x.f;
}
// tanh(x) = 1 - 2/(e^{2x}+1); exact at +-inf, ~1e-7 rel err (v_rcp_f32)
__device__ __forceinline__ float fast_tanh(float x) {
    float e = __expf(x + x);
    float r = __builtin_amdgcn_rcpf(e + 1.0f);
    return fmaf(-2.0f, r, 1.0f);
}

// ------------- weight convert: slabs [Kw1, Qw1, Kw2, Qw2] -------------
__global__ __launch_bounds__(256) void convert_w4(const float* __restrict__ kw1,
                                                  const float* __restrict__ kw2,
                                                  const float* __restrict__ qw1,
                                                  const float* __restrict__ qw2,
                                                  unsigned short* __restrict__ out) {
    int sel = blockIdx.y;   // 0:Kw1 1:Qw1 2:Kw2 3:Qw2
    const float* src = sel == 0 ? kw1 : (sel == 1 ? qw1 : (sel == 2 ? kw2 : qw2));
    int i = blockIdx.x * 256 + threadIdx.x;
    float4 v = reinterpret_cast<const float4*>(src)[i];
    u16x4 o = { f2bf(v.x), f2bf(v.y), f2bf(v.z), f2bf(v.w) };
    reinterpret_cast<u16x4*>(out + (size_t)sel * DIM * DIM)[i] = o;
}

// ---------------- xb[b][s][d] = bf16(seq[s][b][d]) ----------------
__global__ __launch_bounds__(256) void make_xb(const float* __restrict__ seq,
                                               unsigned short* __restrict__ xb) {
    int sb = blockIdx.x;
    int s = sb >> 3, b = sb & 7;
    const float4* src = reinterpret_cast<const float4*>(seq + (size_t)sb * DIM);
    u16x4* dst = reinterpret_cast<u16x4*>(xb + ((size_t)b * SEQ + s) * DIM);
    int t = threadIdx.x;
    float4 v = src[t];
    u16x4 o = { f2bf(v.x), f2bf(v.y), f2bf(v.z), f2bf(v.w) };
    dst[t] = o;
}

// ---------------- xbT[b][d][s] = bf16(seq[s][b][d]) ----------------
__global__ __launch_bounds__(256) void make_xbT(const float* __restrict__ seq,
                                                unsigned short* __restrict__ xbT) {
    __shared__ unsigned short tile[64][65];
    int s0 = blockIdx.x * 64, d0 = blockIdx.y * 64, b = blockIdx.z;
    int t = threadIdx.x;
    int dx = (t & 15) * 4, sy = t >> 4;
    #pragma unroll
    for (int i = 0; i < 4; ++i) {
        int s = s0 + sy + i * 16;
        float4 v = *reinterpret_cast<const float4*>(seq + ((size_t)s * NB + b) * DIM + d0 + dx);
        tile[sy + i * 16][dx + 0] = f2bf(v.x);
        tile[sy + i * 16][dx + 1] = f2bf(v.y);
        tile[sy + i * 16][dx + 2] = f2bf(v.z);
        tile[sy + i * 16][dx + 3] = f2bf(v.w);
    }
    __syncthreads();
    int sx = (t & 15) * 4, dy = t >> 4;
    #pragma unroll
    for (int i = 0; i < 4; ++i) {
        int d = d0 + dy + i * 16;
        u16x4 o = { tile[sx + 0][dy + i * 16], tile[sx + 1][dy + i * 16],
                    tile[sx + 2][dy + i * 16], tile[sx + 3][dy + i * 16] };
        *reinterpret_cast<u16x4*>(xbT + ((size_t)b * DIM + d) * SEQ + s0 + sx) = o;
    }
}

// ---------------- rowsum zero ----------------
__global__ __launch_bounds__(256) void zero_rowsum(float* __restrict__ rs) {
    rs[blockIdx.x * 256 + threadIdx.x] = 0.0f;
}

// =====================  256x256 8-phase GEMM (r6 ring)  =====
// MODE 0: C bf16 = tanh(acc)            (+sC*bz)
// MODE 3: C bf16 = exp(acc*scale); per-row partial sums atomicAdd -> rowsum[bz*SEQ+row]
// MODE 4: C f32  = acc / rowsum[bz*SEQ+row]   (+sC*bz)
__device__ __forceinline__ void gload16(const unsigned short* g, unsigned short* l) {
    __builtin_amdgcn_global_load_lds((const __attribute__((address_space(1))) void*)g,
                                     (__attribute__((address_space(3))) void*)l,
                                     16, 0, 0);
}

#define MFMA16(I0, J0)                                                                            \
    _Pragma("unroll")                                                                             \
    for (int ks = 0; ks < 2; ++ks)                                                                \
        _Pragma("unroll")                                                                         \
        for (int ii = 0; ii < 4; ++ii)                                                            \
            _Pragma("unroll")                                                                     \
            for (int jj = 0; jj < 2; ++jj)                                                        \
                acc[I0 + ii][J0 + jj] = __builtin_amdgcn_mfma_f32_16x16x32_bf16(                   \
                    a[I0 + ii][ks], b[J0 + jj][ks], acc[I0 + ii][J0 + jj], 0, 0, 0);

template<int MODE>
__global__ __launch_bounds__(512, 2) void gemm256(
    const unsigned short* __restrict__ A, size_t sA, int lda,
    const unsigned short* __restrict__ B, size_t sB, int ldb,
    void* __restrict__ Cv, size_t sC, int ldc,
    int K, float scale, float* __restrict__ rowsum)
{
    __shared__ unsigned short AsF[2 * 2 * 8192];
    __shared__ unsigned short BsF[2 * 2 * 8192];

    // ---- T1: bijective XCD swizzle (all grids divisible by 8) ----
    const int gx = gridDim.x, gy = gridDim.y;
    const int nwg = gx * gy * gridDim.z;
    const int fid = blockIdx.x + gx * (blockIdx.y + gy * blockIdx.z);
    const int cpx = nwg >> 3;
    const int sw = (fid & 7) * cpx + (fid >> 3);
    const int bx = sw % gx;
    const int rem = sw / gx;
    const int by = rem % gy;
    const int bz = rem / gy;

    const unsigned short* Ab = A + sA * bz;
    const unsigned short* Bb = B + sB * bz;
    const int m0 = by * 256;
    const int n0 = bx * 256;

    const int t_ = threadIdx.x;
    const int lane = t_ & 63;
    const int w = t_ >> 6;
    const int wm = w >> 2;
    const int wn = w & 3;

    const int l3 = lane >> 3;
    const int g7 = lane & 7;
    const size_t h128a = (size_t)128 * lda, r8a = (size_t)8 * lda;
    const size_t h128b = (size_t)128 * ldb, r8b = (size_t)8 * ldb;
    // pre-swizzled source: LDS[row][g] holds global[row][g ^ (row&7)]
    const unsigned short* gA = Ab + (size_t)(m0 + w * 16 + l3) * lda + ((g7 ^ l3) << 3);
    const unsigned short* gB = Bb + (size_t)(n0 + w * 16 + l3) * ldb + ((g7 ^ l3) << 3);

    const int fr = lane & 15;
    const int hi4 = lane >> 4;
    const int off0 = fr * 64 + (((hi4) ^ g7) << 3);
    const int off1 = fr * 64 + (((4 + hi4) ^ g7) << 3);
    const int bno = (wn & 1) * 4096;
    const int wlds = w * 1024;

    f32x4 acc[8][4] = {};
    const int NT = K >> 6;

    // ---- prologue: tile0 {A0,A1,B0,B1} -> buf0; tile1 {B0,B1} -> buf1 ----
    gload16(gA, AsF + wlds);                     gload16(gA + r8a, AsF + wlds + 512);
    gload16(gA + h128a, AsF + 8192 + wlds);      gload16(gA + h128a + r8a, AsF + 8192 + wlds + 512);
    gload16(gB, BsF + wlds);                     gload16(gB + r8b, BsF + wlds + 512);
    gload16(gB + h128b, BsF + 8192 + wlds);      gload16(gB + h128b + r8b, BsF + 8192 + wlds + 512);
    {
        const unsigned short* gb1 = gB + 64;
        gload16(gb1, BsF + 16384 + wlds);                gload16(gb1 + r8b, BsF + 16384 + wlds + 512);
        gload16(gb1 + h128b, BsF + 16384 + 8192 + wlds); gload16(gb1 + h128b + r8b, BsF + 16384 + 8192 + wlds + 512);
    }
    asm volatile("s_waitcnt vmcnt(4)" ::: "memory");
    __builtin_amdgcn_s_barrier();

    const unsigned short* gA1 = gA + 64;
    const unsigned short* gB2 = gB + 128;

    for (int u = 0; u < NT; ++u) {
        const int bu = (u & 1) * 16384;
        const int bn = 16384 - bu;
        const unsigned short* pA = AsF + bu + wm * 8192;
        const unsigned short* pB = BsF + bu + (wn >> 1) * 8192 + bno;
        const bool pfA = (u + 1 < NT);
        const bool pfB = (u + 2 < NT);
        bf16x8 a[8][2], b[4][2];

        // ---------- Ph0: read a0-3 + b01 ; stage A0(u+1) ; MFMA q00 ----------
        #pragma unroll
        for (int i = 0; i < 4; ++i) {
            a[i][0] = *(const bf16x8*)&pA[i * 1024 + off0];
            a[i][1] = *(const bf16x8*)&pA[i * 1024 + off1];
        }
        #pragma unroll
        for (int j = 0; j < 2; ++j) {
            b[j][0] = *(const bf16x8*)&pB[j * 1024 + off0];
            b[j][1] = *(const bf16x8*)&pB[j * 1024 + off1];
        }
        if (pfA) { gload16(gA1, AsF + bn + wlds); gload16(gA1 + r8a, AsF + bn + wlds + 512); }
        asm volatile("s_waitcnt lgkmcnt(8)" ::: "memory");
        __builtin_amdgcn_s_barrier();
        asm volatile("s_waitcnt lgkmcnt(0)" ::: "memory");
        __builtin_amdgcn_sched_barrier(0);
        __builtin_amdgcn_s_setprio(1);
        MFMA16(0, 0)
        __builtin_amdgcn_s_setprio(0);
        __builtin_amdgcn_s_barrier();

        // ---------- Ph1: read b23 ; stage A1(u+1) ; MFMA q01 ----------
        #pragma unroll
        for (int j = 2; j < 4; ++j) {
            b[j][0] = *(const bf16x8*)&pB[j * 1024 + off0];
            b[j][1] = *(const bf16x8*)&pB[j * 1024 + off1];
        }
        if (pfA) { gload16(gA1 + h128a, AsF + bn + 8192 + wlds); gload16(gA1 + h128a + r8a, AsF + bn + 8192 + wlds + 512); }
        __builtin_amdgcn_s_barrier();
        asm volatile("s_waitcnt lgkmcnt(0)" ::: "memory");
        __builtin_amdgcn_sched_barrier(0);
        __builtin_amdgcn_s_setprio(1);
        MFMA16(0, 2)
        __builtin_amdgcn_s_setprio(0);
        __builtin_amdgcn_s_barrier();

        // ---------- Ph2: read a4-7 ; stage B0(u+2) ; MFMA q10 ----------
        #pragma unroll
        for (int i = 4; i < 8; ++i) {
            a[i][0] = *(const bf16x8*)&pA[i * 1024 + off0];
            a[i][1] = *(const bf16x8*)&pA[i * 1024 + off1];
        }
        if (pfB) { gload16(gB2, BsF + bu + wlds); gload16(gB2 + r8b, BsF + bu + wlds + 512); }
        __builtin_amdgcn_s_barrier();
        asm volatile("s_waitcnt lgkmcnt(0)" ::: "memory");
        __builtin_amdgcn_sched_barrier(0);
        __builtin_amdgcn_s_setprio(1);
        MFMA16(4, 0)
        __builtin_amdgcn_s_setprio(0);
        __builtin_amdgcn_s_barrier();

        // ---------- Ph3: stage B1(u+2) ; vmcnt ; MFMA q11 ----------
        if (pfB) {
            gload16(gB2 + h128b, BsF + bu + 8192 + wlds);
            gload16(gB2 + h128b + r8b, BsF + bu + 8192 + wlds + 512);
            asm volatile("s_waitcnt vmcnt(4)" ::: "memory");
        } else {
            asm volatile("s_waitcnt vmcnt(0)" ::: "memory");
        }
        __builtin_amdgcn_s_barrier();
        __builtin_amdgcn_sched_barrier(0);
        __builtin_amdgcn_s_setprio(1);
        MFMA16(4, 2)
        __builtin_amdgcn_s_setprio(0);
        __builtin_amdgcn_s_barrier();

        gA1 += 64; gB2 += 64;
    }

    // ---- epilogue: C/D layout col=lane&15, row=(lane>>4)*4+r ----
    if (MODE == 0) {
        unsigned short* C = reinterpret_cast<unsigned short*>(Cv) + sC * bz;
        #pragma unroll
        for (int mi = 0; mi < 8; ++mi)
            #pragma unroll
            for (int ni = 0; ni < 4; ++ni)
                #pragma unroll
                for (int r = 0; r < 4; ++r) {
                    int row = m0 + wm * 128 + mi * 16 + hi4 * 4 + r;
                    int col = n0 + wn * 64 + ni * 16 + fr;
                    C[(size_t)row * ldc + col] = f2bf(fast_tanh(acc[mi][ni][r]));
                }
    } else if (MODE == 3) {
        unsigned short* C = reinterpret_cast<unsigned short*>(Cv) + sC * bz;
        #pragma unroll
        for (int mi = 0; mi < 8; ++mi)
            #pragma unroll
            for (int r = 0; r < 4; ++r) {
                int row = m0 + wm * 128 + mi * 16 + hi4 * 4 + r;
                float ps = 0.f;
                #pragma unroll
                for (int ni = 0; ni < 4; ++ni) {
                    unsigned short h = f2bf(__expf(acc[mi][ni][r] * scale));
                    C[(size_t)row * ldc + (n0 + wn * 64 + ni * 16 + fr)] = h;
                    ps += bf2f(h);
                }
                ps += __shfl_xor(ps, 1, 64);
                ps += __shfl_xor(ps, 2, 64);
                ps += __shfl_xor(ps, 4, 64);
                ps += __shfl_xor(ps, 8, 64);
                if (fr == 0) atomicAdd(&rowsum[(size_t)bz * SEQ + row], ps);
            }
    } else {
        float* C = reinterpret_cast<float*>(Cv) + sC * bz;
        #pragma unroll
        for (int mi = 0; mi < 8; ++mi)
            #pragma unroll
            for (int r = 0; r < 4; ++r) {
                int row = m0 + wm * 128 + mi * 16 + hi4 * 4 + r;
                float invs = 1.0f / rowsum[(size_t)bz * SEQ + row];
                #pragma unroll
                for (int ni = 0; ni < 4; ++ni) {
                    int col = n0 + wn * 64 + ni * 16 + fr;
                    C[(size_t)row * ldc + col] = acc[mi][ni][r] * invs;
                }
            }
    }
}

// ---------------- launch ----------------
extern "C" void kernel_launch(void* const* d_in, const int* in_sizes, int n_in,
                              void* d_out, int out_size, void* d_ws, size_t ws_size,
                              hipStream_t stream) {
    const float* seq  = (const float*)d_in[0];
    const float* Kw1f = (const float*)d_in[1];
    const float* Kw2f = (const float*)d_in[2];
    const float* Qw1f = (const float*)d_in[3];
    const float* Qw2f = (const float*)d_in[4];
    float* out = (float*)d_out;

    // Workspace (168 MiB):
    //   [0,8)    W slabs [Kw1,Qw1,Kw2,Qw2]   (dead after MLP2; rowsum reuses offset 0)
    //   [8,40)   xb                          (dead after MLP1)
    //   [40,104) hKQ  [16384 x 2048]         (dead after MLP2)
    //   [104,168) keysqrs [2][8][2048][1024]
    //   P  @ [8,72)   (aliases xb + hKQ-low)
    //   xbT@ [72,104) (aliases hKQ-high)
    char* ws = (char*)d_ws;
    const size_t MB = 1024 * 1024;
    unsigned short* W    = (unsigned short*)(ws);
    unsigned short* Wkq1 = W;                                  // [2048,1024]
    unsigned short* Wk2s = W + 2 * (size_t)DIM * DIM;          // Wk2 then Wq2
    unsigned short* xb   = (unsigned short*)(ws + 8 * MB);
    unsigned short* hKQ  = (unsigned short*)(ws + 40 * MB);
    unsigned short* kq   = (unsigned short*)(ws + 104 * MB);   // keys then qrs
    unsigned short* P    = (unsigned short*)(ws + 8 * MB);
    unsigned short* xbT  = (unsigned short*)(ws + 72 * MB);
    float* rowsum        = (float*)(ws);                       // 64 KB, W dead by then

    convert_w4<<<dim3(DIM * DIM / 4 / 256, 4), 256, 0, stream>>>(Kw1f, Kw2f, Qw1f, Qw2f, W);
    make_xb<<<SEQ * NB, 256, 0, stream>>>(seq, xb);

    // MLP1 merged: hKQ[16384,2048] = tanh(xb @ [Wk1;Qw1]^T)
    gemm256<0><<<dim3(2 * DIM / 256, (NB * SEQ) / 256, 1), 512, 0, stream>>>(
        xb, 0, DIM, Wkq1, 0, DIM, hKQ, 0, 2 * DIM, DIM, 1.0f, nullptr);

    // MLP2 batched z=2: keys = tanh(hK @ Wk2^T), qrs = tanh(hQ @ Wq2^T)
    gemm256<0><<<dim3(DIM / 256, (NB * SEQ) / 256, 2), 512, 0, stream>>>(
        hKQ, (size_t)DIM, 2 * DIM, Wk2s, (size_t)DIM * DIM, DIM,
        kq, (size_t)NB * SEQ * DIM, DIM, DIM, 1.0f, nullptr);

    zero_rowsum<<<NB * SEQ / 256, 256, 0, stream>>>(rowsum);
    make_xbT<<<dim3(SEQ / 64, DIM / 64, NB), 256, 0, stream>>>(seq, xbT);

    // QK: P[b,s,t] = exp(keys[b,s,:].qrs[b,t,:]/32), rowsum accumulated
    gemm256<3><<<dim3(SEQ / 256, SEQ / 256, NB), 512, 0, stream>>>(
        kq, (size_t)SEQ * DIM, DIM, kq + (size_t)NB * SEQ * DIM, (size_t)SEQ * DIM, DIM,
        P, (size_t)SEQ * SEQ, SEQ, DIM, 0.03125f, rowsum);

    // PV: out[s,b,:] = (P[b,s,:] @ x[b]) / rowsum[b,s]
    gemm256<4><<<dim3(DIM / 256, SEQ / 256, NB), 512, 0, stream>>>(
        P, (size_t)SEQ * SEQ, SEQ, xbT, (size_t)DIM * SEQ, SEQ,
        out, (size_t)DIM, NB * DIM, SEQ, 1.0f, rowsum);
}